// Round 1
// baseline (266.733 us; speedup 1.0000x reference)
//
#include <hip/hip_runtime.h>

// TSB RNN, wave-per-row affine scan, LDS-transposed I/O (own row only).
//
// Per-step linear part is anti-diagonal => over step-PAIRS the map is
// diagonal: c1 -> P*c1 + U, c2 -> Q*c2 + V (independent 1-D affine scans).
// Wave (64 lanes) owns one row; processes T=4096 in 4 tiles of 1024 steps
// (16 steps/lane), carrying (C1,C2) across tiles.
//
// Own-row global I/O is lane-stride-1 coalesced (float4); the global<->
// lane-chunk transpose goes through a per-wave private padded LDS region
// (+1 dword per 16 elements => 2-way max bank aliasing, which is free).
// The shared row-0 tile (the X_t quirk) is identical for every wave on the
// chip, so it is NOT staged through LDS: each lane loads its contiguous
// 64 B X-chunk directly from global (L1/L2-hot after first touch). This
// halves LDS (34,816 -> 17,408 B/block), lifting the residency cap from
// 4 to 8 blocks/CU => whole grid co-resident (32 waves/CU) at VGPR<=64.
// No __syncthreads needed: LDS regions are wave-private, DS ops in-order.

constexpr int T_LEN  = 4096;
constexpr int TILE   = 1024;
constexpr int NTILE  = T_LEN / TILE;     // 4
constexpr int CHUNK  = TILE / 64;        // 16 steps per lane per tile
constexpr int WPB    = 4;                // waves per 256-thread block
constexpr int PADREG = TILE + TILE / 16; // 1088 dwords per padded region

__global__ __launch_bounds__(256, 8) void tsb_scan_kernel(
    const float* __restrict__ x,       // (B, T)
    const float* __restrict__ alpha_p,
    const float* __restrict__ beta_p,
    float* __restrict__ out,           // (B, T)
    int B)
{
    __shared__ float lds[WPB * PADREG];   // 17,408 B / block

    const int tid  = threadIdx.x;
    const int wave = tid >> 6;
    const int lane = tid & 63;
    const int row  = blockIdx.x * WPB + wave;
    if (row >= B) return;

    float* xl = &lds[wave * PADREG];      // own-row tile (reused for output)

    const float a   = alpha_p[0];
    const float b   = beta_p[0];
    const float oma = 1.0f - a;
    const float omb = 1.0f - b;

    float C1 = 0.f, C2 = 0.f;             // carry across tiles

    for (int t = 0; t < NTILE; ++t) {
        const float4* xr4 = (const float4*)(x + (size_t)row * T_LEN + t * TILE);
        const float4* Xr4 = (const float4*)(x + t * TILE);

        // ---- own row: coalesced global loads (full lines) ----
        float xs[16];
#pragma unroll
        for (int i = 0; i < 4; ++i)
            *(float4*)(xs + 4 * i) = xr4[i * 64 + lane];

        // ---- row 0 (shared X_t): per-lane contiguous chunk, direct from
        //      global. Same 4 KB for every wave => L1/L2-hot; every 128 B
        //      line fully consumed across the 4 loads. ----
        float Xc[CHUNK];
#pragma unroll
        for (int m = 0; m < 4; ++m)
            *(float4*)(Xc + 4 * m) = Xr4[4 * lane + m];

        // ---- scatter own row to padded LDS ----
#pragma unroll
        for (int j = 0; j < 16; ++j) {
            int e  = (j >> 2) * 256 + 4 * lane + (j & 3); // element idx in tile
            int ap = e + (e >> 4);                        // padded addr
            xl[ap] = xs[j];
        }
        // ---- gather per-lane contiguous chunk (stride-17 base) ----
        float xc[CHUNK];
        const int cb = 17 * lane;
#pragma unroll
        for (int j = 0; j < CHUNK; ++j)
            xc[j] = xl[cb + j];

        // ---- phase 1: compose 8 step-pairs into (p,u | q,v) ----
        float p = 1.f, u = 0.f, q = 1.f, v = 0.f;
#pragma unroll
        for (int h = 0; h < CHUNK / 2; ++h) {
            float x1 = xc[2 * h], x2 = xc[2 * h + 1];
            float X1 = Xc[2 * h], X2 = Xc[2 * h + 1];
            float nz1 = (x1 != 0.f) ? 1.f : 0.f;
            float nz2 = (x2 != 0.f) ? 1.f : 0.f;
            float k1  = (x1 != 0.f) ? oma : 1.f;
            float k2  = (x2 != 0.f) ? oma : 1.f;
            float P = omb * k1;
            float U = omb * a * nz1 * X1 + b * nz2;
            float Q = omb * k2;
            float V = b * k2 * nz1 + a * nz2 * X2;
            u = P * u + U;  p = P * p;
            v = Q * v + V;  q = Q * q;
        }

        // ---- phase 2: inclusive shuffle scan over 64 lanes ----
#pragma unroll
        for (int off = 1; off < 64; off <<= 1) {
            float pi = __shfl_up(p, off, 64);
            float ui = __shfl_up(u, off, 64);
            float qi = __shfl_up(q, off, 64);
            float vi = __shfl_up(v, off, 64);
            if (lane >= off) {
                u = p * ui + u;  p = p * pi;
                v = q * vi + v;  q = q * qi;
            }
        }
        // lane entry state = exclusive prefix applied to tile carry
        float pp = __shfl_up(p, 1, 64), up = __shfl_up(u, 1, 64);
        float qp = __shfl_up(q, 1, 64), vp = __shfl_up(v, 1, 64);
        float c1 = (lane == 0) ? C1 : (pp * C1 + up);
        float c2 = (lane == 0) ? C2 : (qp * C2 + vp);
        // tile exit carry from lane 63's inclusive map (uses OLD C1,C2)
        float p63 = __shfl(p, 63, 64), u63 = __shfl(u, 63, 64);
        float q63 = __shfl(q, 63, 64), v63 = __shfl(v, 63, 64);
        float C1n = p63 * C1 + u63;
        float C2n = q63 * C2 + v63;
        C1 = C1n;  C2 = C2n;

        // ---- phase 3: exact replay; outputs overwrite own chunk in LDS ----
#pragma unroll
        for (int j = 0; j < CHUNK; ++j) {
            float xj = xc[j];
            bool  nz = (xj != 0.f);
            float c2n = nz ? (a * Xc[j] + oma * c1) : c1;
            float c1n = (nz ? b : 0.f) + omb * c2;
            c1 = c1n;  c2 = c2n;
            xl[cb + j] = c1 * c2;
        }

        // ---- coalesced global stores (full lines) ----
        float4* or4 = (float4*)(out + (size_t)row * T_LEN + t * TILE);
#pragma unroll
        for (int i = 0; i < 4; ++i) {
            float os[4];
#pragma unroll
            for (int k = 0; k < 4; ++k) {
                int e = i * 256 + 4 * lane + k;
                os[k] = xl[e + (e >> 4)];
            }
            or4[i * 64 + lane] = *(float4*)os;
        }
    }
}

extern "C" void kernel_launch(void* const* d_in, const int* in_sizes, int n_in,
                              void* d_out, int out_size, void* d_ws, size_t ws_size,
                              hipStream_t stream) {
    const float* x     = (const float*)d_in[0];
    const float* alpha = (const float*)d_in[1];
    const float* beta  = (const float*)d_in[2];
    float* out = (float*)d_out;

    const int B = in_sizes[0] / T_LEN;   // 8192
    const int blocks = (B + WPB - 1) / WPB;
    tsb_scan_kernel<<<blocks, 64 * WPB, 0, stream>>>(x, alpha, beta, out, B);
}

// Round 2
// 237.671 us; speedup vs baseline: 1.1223x; 1.1223x over previous
//
#include <hip/hip_runtime.h>

// TSB RNN, wave-per-row affine scan, LDS-transposed I/O (own row only).
//
// Per-step linear part is anti-diagonal => over step-PAIRS the map is
// diagonal: c1 -> P*c1 + U, c2 -> Q*c2 + V (independent 1-D affine scans).
// Wave (64 lanes) owns one row; processes T=4096 in 4 tiles of 1024 steps
// (16 steps/lane), carrying (C1,C2) across tiles.
//
// Own-row global I/O is lane-stride-1 coalesced (float4); the global<->
// lane-chunk transpose goes through a per-wave private padded LDS region
// (+1 dword per 16 elements => 2-way max bank aliasing, which is free).
// The shared row-0 tile (the X_t quirk) is identical for every wave on the
// chip, so it is NOT staged through LDS: each lane loads its contiguous
// 64 B X-chunk directly from global (L1/L2-hot after first touch). This
// halves LDS (34,816 -> 17,408 B/block): LDS allows 9 blocks/CU.
//
// NOTE on launch bounds: plain __launch_bounds__(256). Adding a min-waves
// hint (256,8) made the allocator squeeze to 32 VGPR and SPILL the per-lane
// arrays to scratch (+200 MB HBM traffic, 110 us vs 85 us). With no hint the
// allocator lands at 64 VGPR spill-free (round-0 evidence with a larger live
// set), which still permits 8 waves/EU = full-grid co-residency.
// No __syncthreads needed: LDS regions are wave-private, DS ops in-order.

constexpr int T_LEN  = 4096;
constexpr int TILE   = 1024;
constexpr int NTILE  = T_LEN / TILE;     // 4
constexpr int CHUNK  = TILE / 64;        // 16 steps per lane per tile
constexpr int WPB    = 4;                // waves per 256-thread block
constexpr int PADREG = TILE + TILE / 16; // 1088 dwords per padded region

__global__ __launch_bounds__(256) void tsb_scan_kernel(
    const float* __restrict__ x,       // (B, T)
    const float* __restrict__ alpha_p,
    const float* __restrict__ beta_p,
    float* __restrict__ out,           // (B, T)
    int B)
{
    __shared__ float lds[WPB * PADREG];   // 17,408 B / block

    const int tid  = threadIdx.x;
    const int wave = tid >> 6;
    const int lane = tid & 63;
    const int row  = blockIdx.x * WPB + wave;
    if (row >= B) return;

    float* xl = &lds[wave * PADREG];      // own-row tile (reused for output)

    const float a   = alpha_p[0];
    const float b   = beta_p[0];
    const float oma = 1.0f - a;
    const float omb = 1.0f - b;

    float C1 = 0.f, C2 = 0.f;             // carry across tiles

    for (int t = 0; t < NTILE; ++t) {
        const float4* xr4 = (const float4*)(x + (size_t)row * T_LEN + t * TILE);
        const float4* Xr4 = (const float4*)(x + t * TILE);

        // ---- own row: coalesced global loads (full lines) ----
        float xs[16];
#pragma unroll
        for (int i = 0; i < 4; ++i)
            *(float4*)(xs + 4 * i) = xr4[i * 64 + lane];

        // ---- row 0 (shared X_t): per-lane contiguous chunk, direct from
        //      global. Same 4 KB for every wave => L1/L2-hot; every 128 B
        //      line fully consumed across the 4 loads. ----
        float Xc[CHUNK];
#pragma unroll
        for (int m = 0; m < 4; ++m)
            *(float4*)(Xc + 4 * m) = Xr4[4 * lane + m];

        // ---- scatter own row to padded LDS ----
#pragma unroll
        for (int j = 0; j < 16; ++j) {
            int e  = (j >> 2) * 256 + 4 * lane + (j & 3); // element idx in tile
            int ap = e + (e >> 4);                        // padded addr
            xl[ap] = xs[j];
        }
        // ---- gather per-lane contiguous chunk (stride-17 base) ----
        float xc[CHUNK];
        const int cb = 17 * lane;
#pragma unroll
        for (int j = 0; j < CHUNK; ++j)
            xc[j] = xl[cb + j];

        // ---- phase 1: compose 8 step-pairs into (p,u | q,v) ----
        float p = 1.f, u = 0.f, q = 1.f, v = 0.f;
#pragma unroll
        for (int h = 0; h < CHUNK / 2; ++h) {
            float x1 = xc[2 * h], x2 = xc[2 * h + 1];
            float X1 = Xc[2 * h], X2 = Xc[2 * h + 1];
            float nz1 = (x1 != 0.f) ? 1.f : 0.f;
            float nz2 = (x2 != 0.f) ? 1.f : 0.f;
            float k1  = (x1 != 0.f) ? oma : 1.f;
            float k2  = (x2 != 0.f) ? oma : 1.f;
            float P = omb * k1;
            float U = omb * a * nz1 * X1 + b * nz2;
            float Q = omb * k2;
            float V = b * k2 * nz1 + a * nz2 * X2;
            u = P * u + U;  p = P * p;
            v = Q * v + V;  q = Q * q;
        }

        // ---- phase 2: inclusive shuffle scan over 64 lanes ----
#pragma unroll
        for (int off = 1; off < 64; off <<= 1) {
            float pi = __shfl_up(p, off, 64);
            float ui = __shfl_up(u, off, 64);
            float qi = __shfl_up(q, off, 64);
            float vi = __shfl_up(v, off, 64);
            if (lane >= off) {
                u = p * ui + u;  p = p * pi;
                v = q * vi + v;  q = q * qi;
            }
        }
        // lane entry state = exclusive prefix applied to tile carry
        float pp = __shfl_up(p, 1, 64), up = __shfl_up(u, 1, 64);
        float qp = __shfl_up(q, 1, 64), vp = __shfl_up(v, 1, 64);
        float c1 = (lane == 0) ? C1 : (pp * C1 + up);
        float c2 = (lane == 0) ? C2 : (qp * C2 + vp);
        // tile exit carry from lane 63's inclusive map (uses OLD C1,C2)
        float p63 = __shfl(p, 63, 64), u63 = __shfl(u, 63, 64);
        float q63 = __shfl(q, 63, 64), v63 = __shfl(v, 63, 64);
        float C1n = p63 * C1 + u63;
        float C2n = q63 * C2 + v63;
        C1 = C1n;  C2 = C2n;

        // ---- phase 3: exact replay; outputs overwrite own chunk in LDS ----
#pragma unroll
        for (int j = 0; j < CHUNK; ++j) {
            float xj = xc[j];
            bool  nz = (xj != 0.f);
            float c2n = nz ? (a * Xc[j] + oma * c1) : c1;
            float c1n = (nz ? b : 0.f) + omb * c2;
            c1 = c1n;  c2 = c2n;
            xl[cb + j] = c1 * c2;
        }

        // ---- coalesced global stores (full lines) ----
        float4* or4 = (float4*)(out + (size_t)row * T_LEN + t * TILE);
#pragma unroll
        for (int i = 0; i < 4; ++i) {
            float os[4];
#pragma unroll
            for (int k = 0; k < 4; ++k) {
                int e = i * 256 + 4 * lane + k;
                os[k] = xl[e + (e >> 4)];
            }
            or4[i * 64 + lane] = *(float4*)os;
        }
    }
}

extern "C" void kernel_launch(void* const* d_in, const int* in_sizes, int n_in,
                              void* d_out, int out_size, void* d_ws, size_t ws_size,
                              hipStream_t stream) {
    const float* x     = (const float*)d_in[0];
    const float* alpha = (const float*)d_in[1];
    const float* beta  = (const float*)d_in[2];
    float* out = (float*)d_out;

    const int B = in_sizes[0] / T_LEN;   // 8192
    const int blocks = (B + WPB - 1) / WPB;
    tsb_scan_kernel<<<blocks, 64 * WPB, 0, stream>>>(x, alpha, beta, out, B);
}